// Round 12
// baseline (37.496 us; speedup 1.0000x reference)
//
#include <hip/hip_runtime.h>

// LePE window attention, 32x32x16 bf16 MFMA, reg-P via v_permlane32_swap_b32.
// R12: wave-pair kt-split for occupancy. Grid 512 = (window, head, q-half),
// 1024 threads; wave pair shares 32 q rows, half=0 does kt 0-7, half=1 kt 8-15;
// partials merged via LDS (aliased onto dead K_lds). 2 blocks/CU = 32 waves/CU
// (R10 was 1 block/CU = 16). Main-loop body identical to R10 (R11's s_next
// pipeline + sched_barrier regressed and is reverted).
// LDS = K[512][40] + V^T[32][536] bf16 = 73.5 KB; 2x73.5 = 147 <= 160 KB.

namespace {
constexpr int Bn   = 8;
constexpr int Ww   = 64;
constexpr int Cc   = 128;
constexpr int HD   = 32;
constexpr int WSP  = 8;
constexpr int NTOK = 512;
constexpr int LL   = 64 * 64;
// 32^-0.5 * log2(e): exp(s) == exp2(s') with scale folded into Q
constexpr float SCALE_L2E = 0.17677669529663687f * 1.4426950408889634f;
constexpr int KPAD = 40;   // K row stride in shorts (80B rows -> 16B-aligned frags)
constexpr int VPAD = 536;  // V^T row stride in shorts (1072B rows -> 16B-aligned)
}

typedef __bf16 bf16x8 __attribute__((ext_vector_type(8)));
typedef float  f32x16 __attribute__((ext_vector_type(16)));
typedef unsigned int uint32x4 __attribute__((ext_vector_type(4)));

// dst.lo = bf16(x), dst.hi = bf16(y) — single VALU op (RNE)
__device__ inline unsigned cvtpk(float x, float y) {
    unsigned r;
    asm("v_cvt_pk_bf16_f32 %0, %1, %2" : "=v"(r) : "v"(x), "v"(y));
    return r;
}

__global__ __launch_bounds__(1024, 8) void attn_kernel(const float* __restrict__ qkv,
                                                       const float* __restrict__ cw,
                                                       const float* __restrict__ cb,
                                                       float* __restrict__ out) {
    const int blk = blockIdx.x;          // 0..511
    const int w   = blk >> 3;            // window 0..63
    const int h   = (blk >> 1) & 3;      // head
    const int qh  = blk & 1;             // q half (256 rows)
    const int b   = w >> 3;
    const int wb  = w & 7;
    const int tid = threadIdx.x;         // 0..1023
    const int wv   = tid >> 6;           // wave 0..15
    const int pair = wv >> 1;            // 8 pairs -> 32 q rows each
    const int half = wv & 1;             // kt range selector
    const int lane = tid & 63;
    const int l31 = lane & 31;
    const int h5  = lane >> 5;

    const float* qp = qkv;
    const float* kp = qkv + (size_t)Bn * LL * Cc;
    const float* vp = qkv + (size_t)2 * Bn * LL * Cc;

    __shared__ short K_lds[NTOK][KPAD];
    __shared__ short VT_lds[HD][VPAD];

    // ---- Q fragments: q tok = qh*256 + pair*32 + l31, d = dc*16 + h5*8 + e ----
    const int qtok = qh * 256 + pair * 32 + l31;
    const int qlqi = (qtok >> 3) * Ww + wb * WSP + (qtok & 7);
    bf16x8 qf[2];
    {
        const float* p = qp + ((size_t)b * LL + qlqi) * Cc + h * HD + h5 * 8;
#pragma unroll
        for (int dc = 0; dc < 2; ++dc) {
            float4 a = *reinterpret_cast<const float4*>(p + dc * 16);
            float4 c = *reinterpret_cast<const float4*>(p + dc * 16 + 4);
            uint32x4 u;
            u.x = cvtpk(a.x * SCALE_L2E, a.y * SCALE_L2E);
            u.y = cvtpk(a.z * SCALE_L2E, a.w * SCALE_L2E);
            u.z = cvtpk(c.x * SCALE_L2E, c.y * SCALE_L2E);
            u.w = cvtpk(c.z * SCALE_L2E, c.w * SCALE_L2E);
            qf[dc] = __builtin_bit_cast(bf16x8, u);
        }
    }

    // ---- stage K and V^T (bf16), token-pair scheme: 2048 items / 1024 thr ----
    for (int i = tid; i < (NTOK / 2) * 8; i += 1024) {
        const int tp = i >> 3, j = i & 7;      // token pair, d-group
        const int t0 = tp * 2, t1 = t0 + 1;
        const int lqi0 = (t0 >> 3) * Ww + wb * WSP + (t0 & 7);  // lqi1 = lqi0+1
        const size_t b0 = ((size_t)b * LL + lqi0) * Cc + h * HD + j * 4;
        const float4 k0 = *reinterpret_cast<const float4*>(kp + b0);
        const float4 k1 = *reinterpret_cast<const float4*>(kp + b0 + Cc);
        uint2 pk0, pk1;
        pk0.x = cvtpk(k0.x, k0.y);  pk0.y = cvtpk(k0.z, k0.w);
        pk1.x = cvtpk(k1.x, k1.y);  pk1.y = cvtpk(k1.z, k1.w);
        *reinterpret_cast<uint2*>(&K_lds[t0][j * 4]) = pk0;
        *reinterpret_cast<uint2*>(&K_lds[t1][j * 4]) = pk1;
        const float4 v0 = *reinterpret_cast<const float4*>(vp + b0);
        const float4 v1 = *reinterpret_cast<const float4*>(vp + b0 + Cc);
        *reinterpret_cast<unsigned*>(&VT_lds[j * 4 + 0][t0]) = cvtpk(v0.x, v1.x);
        *reinterpret_cast<unsigned*>(&VT_lds[j * 4 + 1][t0]) = cvtpk(v0.y, v1.y);
        *reinterpret_cast<unsigned*>(&VT_lds[j * 4 + 2][t0]) = cvtpk(v0.z, v1.z);
        *reinterpret_cast<unsigned*>(&VT_lds[j * 4 + 3][t0]) = cvtpk(v0.w, v1.w);
    }
    __syncthreads();

    f32x16 acc = (f32x16)(0.f);
    float lsum = 0.f;
    const f32x16 z16 = (f32x16)(0.f);

    auto load_kf = [&](int kt, bf16x8* kf) {
        const int krow = kt * 32 + l31;
#pragma unroll
        for (int dc = 0; dc < 2; ++dc)
            kf[dc] = __builtin_bit_cast(bf16x8,
                *reinterpret_cast<const uint32x4*>(&K_lds[krow][dc * 16 + h5 * 8]));
    };

    const int kt0 = half * 8;            // this wave's kt range: [kt0, kt0+8)
    bf16x8 kf[2];
    load_kf(kt0, kf);

    // ---- main loop: 8 tiles of 32 keys, barrier-free (R10 body) ----
    for (int kt = kt0; kt < kt0 + 8; ++kt) {
        __builtin_amdgcn_s_setprio(1);
        f32x16 s = z16;
        s = __builtin_amdgcn_mfma_f32_32x32x16_bf16(kf[0], qf[0], s, 0, 0, 0);
        s = __builtin_amdgcn_mfma_f32_32x32x16_bf16(kf[1], qf[1], s, 0, 0, 0);
        __builtin_amdgcn_s_setprio(0);
        // lane holds S^T[k][q=l31], k = (reg&3) + 8*(reg>>2) + 4*h5 + kt*32

        // prefetch next kf + this kt's V fragments while s is in flight
        bf16x8 kfn[2];
        load_kf((kt + 1) & 15, kfn);
        uint32x4 vu[2];
#pragma unroll
        for (int kw = 0; kw < 2; ++kw) {
            const int kcol = kt * 32 + kw * 16 + h5 * 8;
            vu[kw] = *reinterpret_cast<const uint32x4*>(&VT_lds[l31][kcol]);
        }

        float pe[16];
#pragma unroll
        for (int i = 0; i < 16; ++i) pe[i] = __builtin_amdgcn_exp2f(s[i]);
        {
            float t0 = 0.f, t1 = 0.f;
#pragma unroll
            for (int i = 0; i < 8; ++i) { t0 += pe[2 * i]; t1 += pe[2 * i + 1]; }
            lsum += t0 + t1;
        }
        unsigned dw[8];
#pragma unroll
        for (int i = 0; i < 8; ++i) dw[i] = cvtpk(pe[2 * i], pe[2 * i + 1]);

        // PV: per 16-key window kw, redistribute P across the h5 halves with
        // 2x v_permlane32_swap_b32 (vdst_hi <-> vsrc_lo), then one MFMA.
#pragma unroll
        for (int kw = 0; kw < 2; ++kw) {
            unsigned a0 = dw[4 * kw + 0], b0 = dw[4 * kw + 2];
            unsigned a1 = dw[4 * kw + 1], b1 = dw[4 * kw + 3];
            asm("v_permlane32_swap_b32 %0, %1" : "+v"(a0), "+v"(b0));
            asm("v_permlane32_swap_b32 %0, %1" : "+v"(a1), "+v"(b1));
            uint32x4 pu; pu.x = a0; pu.y = a1; pu.z = b0; pu.w = b1;
            __builtin_amdgcn_s_setprio(1);
            acc = __builtin_amdgcn_mfma_f32_32x32x16_bf16(
                __builtin_bit_cast(bf16x8, pu), __builtin_bit_cast(bf16x8, vu[kw]),
                acc, 0, 0, 0);
            __builtin_amdgcn_s_setprio(0);
        }
        kf[0] = kfn[0];
        kf[1] = kfn[1];
    }

    // ---- intra-wave: sum the two h5 k-halves ----
    lsum += __shfl_xor(lsum, 32);

    // ---- cross-wave-pair merge via LDS (aliased onto dead K_lds) ----
    // accbuf[8][32][32] f32 (32 KB) + lsbuf[8][32] f32 (1 KB) <= 40 KB K_lds.
    float* accbuf = reinterpret_cast<float*>(&K_lds[0][0]);
    float* lsbuf  = accbuf + 8 * 32 * 32;
    __syncthreads();   // all K_lds fragment reads complete before overwrite
    if (half == 1) {
#pragma unroll
        for (int r = 0; r < 16; ++r) {
            const int c_r = (r & 3) + 8 * (r >> 2);
            accbuf[(pair * 32 + c_r + 4 * h5) * 32 + l31] = acc[r];
        }
        if (lane < 32) lsbuf[pair * 32 + l31] = lsum;
    }
    __syncthreads();
    if (half == 1) return;   // epilogue handled by half=0 waves (no barriers after)

    lsum += lsbuf[pair * 32 + l31];
    const float inv = 1.f / lsum;
#pragma unroll
    for (int r = 0; r < 16; ++r) {
        const int c_r = (r & 3) + 8 * (r >> 2);
        acc[r] += accbuf[(pair * 32 + c_r + 4 * h5) * 32 + l31];
    }

    // ---- LePE conv: lane owns channel d = l31 of head h ----
    const int ch = h * HD + l31;
    float wreg[9];
#pragma unroll
    for (int wi = 0; wi < 9; ++wi) wreg[wi] = cw[ch * 9 + wi];
    const float bias = cb[ch];

    const int tok0 = qh * 256 + pair * 32;
    // Packed V halo: 52 bf16 toks [tok0 + 4*h5 - 12, +40) as 26 uints.
    // Needed tap range rel. tok0+4h5 is [-9,+36]; clamped chunk slots are only
    // tokens <0 / >=512, all rowok-guarded below.
    unsigned hw[26];
    {
        const int segbase = tok0 + 4 * h5 - 12;
#pragma unroll
        for (int c2 = 0; c2 < 13; ++c2) {
            int t = segbase + 4 * c2;
            t = t < 0 ? 0 : (t > NTOK - 4 ? NTOK - 4 : t);
            const uint2 u = *reinterpret_cast<const uint2*>(&VT_lds[l31][t]);
            hw[c2 * 2 + 0] = u.x;
            hw[c2 * 2 + 1] = u.y;
        }
    }

    // ---- epilogue: normalize + conv + store, per accumulator element ----
#pragma unroll
    for (int r = 0; r < 16; ++r) {
        const int c_r = (r & 3) + 8 * (r >> 2);           // q row offset (compile-time)
        const float iv = __shfl(inv, c_r + 4 * h5);       // q_r's denominator
        const int tok = tok0 + c_r + 4 * h5;
        float cv = bias;
#pragma unroll
        for (int dy = -1; dy <= 1; ++dy) {
            const bool rowok = (unsigned)(tok + dy * 8) < (unsigned)NTOK;
#pragma unroll
            for (int dx = -1; dx <= 1; ++dx) {
                const int idx = c_r + 12 + dy * 8 + dx;   // compile-time, in [3,48]
                const unsigned word = hw[idx >> 1];
                const float tap = __builtin_bit_cast(float,
                    (idx & 1) ? (word & 0xFFFF0000u) : (word << 16));
                bool ok = rowok;
                if (dx == -1) ok = ok && (((r & 3) != 0) || (h5 != 0));  // wc > 0
                if (dx == +1) ok = ok && (((r & 3) != 3) || (h5 == 0));  // wc < 7
                cv += ok ? wreg[(dy + 1) * 3 + (dx + 1)] * tap : 0.f;
            }
        }
        const int lqi = (tok >> 3) * Ww + wb * WSP + (tok & 7);
        out[((size_t)b * LL + lqi) * Cc + ch] = acc[r] * iv + cv;
    }
}

extern "C" void kernel_launch(void* const* d_in, const int* in_sizes, int n_in,
                              void* d_out, int out_size, void* d_ws, size_t ws_size,
                              hipStream_t stream) {
    const float* qkv = (const float*)d_in[0];
    const float* cw  = (const float*)d_in[1];
    const float* cb  = (const float*)d_in[2];
    float* out = (float*)d_out;

    attn_kernel<<<512, 1024, 0, stream>>>(qkv, cw, cb, out);
}

// Round 13
// 30.015 us; speedup vs baseline: 1.2492x; 1.2492x over previous
//
#include <hip/hip_runtime.h>

// LePE window attention, 32x32x16 bf16 MFMA, reg-P via v_permlane32_swap_b32.
// R13: revert to R10 body (R11 pipeline and R12 kt-split both regressed; R12's
// launch_bounds(1024,8) proved the 64-VGPR cap forces spills -> 16 waves/CU is
// this algorithm's TLP cap). Two changes vs R10:
//   1) LDS padded 73.5 -> 81.5 KB so TWO blocks can never co-reside on a CU —
//      probes the "dispatcher packs 2 blocks on half the CUs, half idle"
//      hypothesis for the 2x gap between pipe budgets and wall time.
//   2) T14-lite staging: all 12 global loads issued first, cvt/ds_write after,
//      so HBM/L2 latency hides under address calc + Q prep.
// Structure: 256 blocks x 1024 threads (16 waves), K/V staged once per
// (window, head). LDS = K[512][40] + V^T[32][536] bf16 + 8KB pad.

namespace {
constexpr int Bn   = 8;
constexpr int Ww   = 64;
constexpr int Cc   = 128;
constexpr int HD   = 32;
constexpr int WSP  = 8;
constexpr int NTOK = 512;
constexpr int LL   = 64 * 64;
// 32^-0.5 * log2(e): exp(s) == exp2(s') with scale folded into Q
constexpr float SCALE_L2E = 0.17677669529663687f * 1.4426950408889634f;
constexpr int KPAD = 40;   // K row stride in shorts (80B rows -> 16B-aligned frags)
constexpr int VPAD = 536;  // V^T row stride in shorts (1072B rows -> 16B-aligned)
}

typedef __bf16 bf16x8 __attribute__((ext_vector_type(8)));
typedef float  f32x16 __attribute__((ext_vector_type(16)));
typedef unsigned int uint32x4 __attribute__((ext_vector_type(4)));

// dst.lo = bf16(x), dst.hi = bf16(y) — single VALU op (RNE)
__device__ inline unsigned cvtpk(float x, float y) {
    unsigned r;
    asm("v_cvt_pk_bf16_f32 %0, %1, %2" : "=v"(r) : "v"(x), "v"(y));
    return r;
}

__global__ __launch_bounds__(1024, 4) void attn_kernel(const float* __restrict__ qkv,
                                                       const float* __restrict__ cw,
                                                       const float* __restrict__ cb,
                                                       float* __restrict__ out) {
    const int blk = blockIdx.x;          // 0..255
    const int w   = blk >> 2;            // window 0..63
    const int h   = blk & 3;             // head
    const int b   = w >> 3;
    const int wb  = w & 7;
    const int tid = threadIdx.x;         // 0..1023
    const int wv  = tid >> 6;            // wave 0..15 -> 32 q rows each
    const int lane = tid & 63;
    const int l31 = lane & 31;
    const int h5  = lane >> 5;

    const float* qp = qkv;
    const float* kp = qkv + (size_t)Bn * LL * Cc;
    const float* vp = qkv + (size_t)2 * Bn * LL * Cc;

    __shared__ short K_lds[NTOK][KPAD];
    __shared__ short VT_lds[HD][VPAD];
    __shared__ float padlds[2048];       // 8 KB: total 81.5 KB -> 1 block/CU max
    if (tid == 0) ((volatile float*)padlds)[0] = 1.f;   // keep allocation live

    // ---- staging: issue ALL global loads first (T14-lite) ----
    // iter a: i = tid, iter b: i = tid + 1024  (exactly 2 iterations)
    const int tpa = tid >> 3,          ja = tid & 7;
    const int tpb = (tid + 1024) >> 3, jb = (tid + 1024) & 7;
    const int t0a = tpa * 2, t0b = tpb * 2;
    const int lqa = (t0a >> 3) * Ww + wb * WSP + (t0a & 7);
    const int lqb = (t0b >> 3) * Ww + wb * WSP + (t0b & 7);
    const size_t ga = ((size_t)b * LL + lqa) * Cc + h * HD + ja * 4;
    const size_t gb = ((size_t)b * LL + lqb) * Cc + h * HD + jb * 4;
    const float4 k0a = *reinterpret_cast<const float4*>(kp + ga);
    const float4 k1a = *reinterpret_cast<const float4*>(kp + ga + Cc);
    const float4 v0a = *reinterpret_cast<const float4*>(vp + ga);
    const float4 v1a = *reinterpret_cast<const float4*>(vp + ga + Cc);
    const float4 k0b = *reinterpret_cast<const float4*>(kp + gb);
    const float4 k1b = *reinterpret_cast<const float4*>(kp + gb + Cc);
    const float4 v0b = *reinterpret_cast<const float4*>(vp + gb);
    const float4 v1b = *reinterpret_cast<const float4*>(vp + gb + Cc);

    // Q loads issued after (consumed last)
    const int qtok = wv * 32 + l31;      // q tok; d = dc*16 + h5*8 + e
    const int qlqi = (qtok >> 3) * Ww + wb * WSP + (qtok & 7);
    const float* qptr = qp + ((size_t)b * LL + qlqi) * Cc + h * HD + h5 * 8;
    const float4 qa0 = *reinterpret_cast<const float4*>(qptr);
    const float4 qc0 = *reinterpret_cast<const float4*>(qptr + 4);
    const float4 qa1 = *reinterpret_cast<const float4*>(qptr + 16);
    const float4 qc1 = *reinterpret_cast<const float4*>(qptr + 20);

    // ---- convert + LDS write (waits only on the K/V loads) ----
    {
        uint2 pk0, pk1;
        pk0.x = cvtpk(k0a.x, k0a.y);  pk0.y = cvtpk(k0a.z, k0a.w);
        pk1.x = cvtpk(k1a.x, k1a.y);  pk1.y = cvtpk(k1a.z, k1a.w);
        *reinterpret_cast<uint2*>(&K_lds[t0a][ja * 4]) = pk0;
        *reinterpret_cast<uint2*>(&K_lds[t0a + 1][ja * 4]) = pk1;
        *reinterpret_cast<unsigned*>(&VT_lds[ja * 4 + 0][t0a]) = cvtpk(v0a.x, v1a.x);
        *reinterpret_cast<unsigned*>(&VT_lds[ja * 4 + 1][t0a]) = cvtpk(v0a.y, v1a.y);
        *reinterpret_cast<unsigned*>(&VT_lds[ja * 4 + 2][t0a]) = cvtpk(v0a.z, v1a.z);
        *reinterpret_cast<unsigned*>(&VT_lds[ja * 4 + 3][t0a]) = cvtpk(v0a.w, v1a.w);
    }
    {
        uint2 pk0, pk1;
        pk0.x = cvtpk(k0b.x, k0b.y);  pk0.y = cvtpk(k0b.z, k0b.w);
        pk1.x = cvtpk(k1b.x, k1b.y);  pk1.y = cvtpk(k1b.z, k1b.w);
        *reinterpret_cast<uint2*>(&K_lds[t0b][jb * 4]) = pk0;
        *reinterpret_cast<uint2*>(&K_lds[t0b + 1][jb * 4]) = pk1;
        *reinterpret_cast<unsigned*>(&VT_lds[jb * 4 + 0][t0b]) = cvtpk(v0b.x, v1b.x);
        *reinterpret_cast<unsigned*>(&VT_lds[jb * 4 + 1][t0b]) = cvtpk(v0b.y, v1b.y);
        *reinterpret_cast<unsigned*>(&VT_lds[jb * 4 + 2][t0b]) = cvtpk(v0b.z, v1b.z);
        *reinterpret_cast<unsigned*>(&VT_lds[jb * 4 + 3][t0b]) = cvtpk(v0b.w, v1b.w);
    }

    // ---- Q fragments ----
    bf16x8 qf[2];
    {
        uint32x4 u;
        u.x = cvtpk(qa0.x * SCALE_L2E, qa0.y * SCALE_L2E);
        u.y = cvtpk(qa0.z * SCALE_L2E, qa0.w * SCALE_L2E);
        u.z = cvtpk(qc0.x * SCALE_L2E, qc0.y * SCALE_L2E);
        u.w = cvtpk(qc0.z * SCALE_L2E, qc0.w * SCALE_L2E);
        qf[0] = __builtin_bit_cast(bf16x8, u);
        u.x = cvtpk(qa1.x * SCALE_L2E, qa1.y * SCALE_L2E);
        u.y = cvtpk(qa1.z * SCALE_L2E, qa1.w * SCALE_L2E);
        u.z = cvtpk(qc1.x * SCALE_L2E, qc1.y * SCALE_L2E);
        u.w = cvtpk(qc1.z * SCALE_L2E, qc1.w * SCALE_L2E);
        qf[1] = __builtin_bit_cast(bf16x8, u);
    }
    __syncthreads();   // the only barrier

    f32x16 acc = (f32x16)(0.f);
    float lsum = 0.f;
    const f32x16 z16 = (f32x16)(0.f);

    auto load_kf = [&](int kt, bf16x8* kf) {
        const int krow = kt * 32 + l31;
#pragma unroll
        for (int dc = 0; dc < 2; ++dc)
            kf[dc] = __builtin_bit_cast(bf16x8,
                *reinterpret_cast<const uint32x4*>(&K_lds[krow][dc * 16 + h5 * 8]));
    };

    bf16x8 kf[2];
    load_kf(0, kf);

    // ---- main loop: 16 tiles of 32 keys, barrier-free (R10 body) ----
    for (int kt = 0; kt < 16; ++kt) {
        __builtin_amdgcn_s_setprio(1);
        f32x16 s = z16;
        s = __builtin_amdgcn_mfma_f32_32x32x16_bf16(kf[0], qf[0], s, 0, 0, 0);
        s = __builtin_amdgcn_mfma_f32_32x32x16_bf16(kf[1], qf[1], s, 0, 0, 0);
        __builtin_amdgcn_s_setprio(0);
        // lane holds S^T[k][q=l31], k = (reg&3) + 8*(reg>>2) + 4*h5 + kt*32

        // prefetch next kf + this kt's V fragments while s is in flight
        bf16x8 kfn[2];
        load_kf((kt + 1) & 15, kfn);
        uint32x4 vu[2];
#pragma unroll
        for (int kw = 0; kw < 2; ++kw) {
            const int kcol = kt * 32 + kw * 16 + h5 * 8;
            vu[kw] = *reinterpret_cast<const uint32x4*>(&VT_lds[l31][kcol]);
        }

        float pe[16];
#pragma unroll
        for (int i = 0; i < 16; ++i) pe[i] = __builtin_amdgcn_exp2f(s[i]);
        {
            float t0 = 0.f, t1 = 0.f;
#pragma unroll
            for (int i = 0; i < 8; ++i) { t0 += pe[2 * i]; t1 += pe[2 * i + 1]; }
            lsum += t0 + t1;
        }
        unsigned dw[8];
#pragma unroll
        for (int i = 0; i < 8; ++i) dw[i] = cvtpk(pe[2 * i], pe[2 * i + 1]);

        // PV: per 16-key window kw, redistribute P across the h5 halves with
        // 2x v_permlane32_swap_b32 (vdst_hi <-> vsrc_lo), then one MFMA.
#pragma unroll
        for (int kw = 0; kw < 2; ++kw) {
            unsigned a0 = dw[4 * kw + 0], b0 = dw[4 * kw + 2];
            unsigned a1 = dw[4 * kw + 1], b1 = dw[4 * kw + 3];
            asm("v_permlane32_swap_b32 %0, %1" : "+v"(a0), "+v"(b0));
            asm("v_permlane32_swap_b32 %0, %1" : "+v"(a1), "+v"(b1));
            uint32x4 pu; pu.x = a0; pu.y = a1; pu.z = b0; pu.w = b1;
            __builtin_amdgcn_s_setprio(1);
            acc = __builtin_amdgcn_mfma_f32_32x32x16_bf16(
                __builtin_bit_cast(bf16x8, pu), __builtin_bit_cast(bf16x8, vu[kw]),
                acc, 0, 0, 0);
            __builtin_amdgcn_s_setprio(0);
        }
        kf[0] = kfn[0];
        kf[1] = kfn[1];
    }

    // ---- softmax denominator: other k-half lives in the partner lane ----
    lsum += __shfl_xor(lsum, 32);
    const float inv = 1.f / lsum;

    // ---- LePE conv: lane owns channel d = l31 of head h ----
    const int ch = h * HD + l31;
    float wreg[9];
#pragma unroll
    for (int wi = 0; wi < 9; ++wi) wreg[wi] = cw[ch * 9 + wi];
    const float bias = cb[ch];

    const int tok0 = wv * 32;
    // Packed V halo: 52 bf16 toks [tok0 + 4*h5 - 12, +40) as 26 uints.
    // Needed tap range rel. tok0+4h5 is [-9,+36]; clamped chunk slots are only
    // tokens <0 / >=512, all rowok-guarded below.
    unsigned hw[26];
    {
        const int segbase = tok0 + 4 * h5 - 12;
#pragma unroll
        for (int c2 = 0; c2 < 13; ++c2) {
            int t = segbase + 4 * c2;
            t = t < 0 ? 0 : (t > NTOK - 4 ? NTOK - 4 : t);
            const uint2 u = *reinterpret_cast<const uint2*>(&VT_lds[l31][t]);
            hw[c2 * 2 + 0] = u.x;
            hw[c2 * 2 + 1] = u.y;
        }
    }

    // ---- epilogue: normalize + conv + store, per accumulator element ----
#pragma unroll
    for (int r = 0; r < 16; ++r) {
        const int c_r = (r & 3) + 8 * (r >> 2);           // q row offset (compile-time)
        const float iv = __shfl(inv, c_r + 4 * h5);       // q_r's denominator
        const int tok = tok0 + c_r + 4 * h5;
        float cv = bias;
#pragma unroll
        for (int dy = -1; dy <= 1; ++dy) {
            const bool rowok = (unsigned)(tok + dy * 8) < (unsigned)NTOK;
#pragma unroll
            for (int dx = -1; dx <= 1; ++dx) {
                const int idx = c_r + 12 + dy * 8 + dx;   // compile-time, in [3,48]
                const unsigned word = hw[idx >> 1];
                const float tap = __builtin_bit_cast(float,
                    (idx & 1) ? (word & 0xFFFF0000u) : (word << 16));
                bool ok = rowok;
                if (dx == -1) ok = ok && (((r & 3) != 0) || (h5 != 0));  // wc > 0
                if (dx == +1) ok = ok && (((r & 3) != 3) || (h5 == 0));  // wc < 7
                cv += ok ? wreg[(dy + 1) * 3 + (dx + 1)] * tap : 0.f;
            }
        }
        const int lqi = (tok >> 3) * Ww + wb * WSP + (tok & 7);
        out[((size_t)b * LL + lqi) * Cc + ch] = acc[r] * iv + cv;
    }
}

extern "C" void kernel_launch(void* const* d_in, const int* in_sizes, int n_in,
                              void* d_out, int out_size, void* d_ws, size_t ws_size,
                              hipStream_t stream) {
    const float* qkv = (const float*)d_in[0];
    const float* cw  = (const float*)d_in[1];
    const float* cb  = (const float*)d_in[2];
    float* out = (float*)d_out;

    attn_kernel<<<256, 1024, 0, stream>>>(qkv, cw, cb, out);
}

// Round 14
// 28.733 us; speedup vs baseline: 1.3050x; 1.0446x over previous
//
#include <hip/hip_runtime.h>

// LePE window attention, 32x32x16 bf16 MFMA, reg-P via v_permlane32_swap_b32.
// R14: (1) ALL s_setprio removed — at 4 homogeneous waves/SIMD, prio-1 MFMA
// clusters starve co-resident waves' exp2/VALU issue (anti-overlap; T5 only
// pays with role-split schedules, m190). (2) lsum computed by a ones-column
// MFMA into lsum_acc — kills 16 VALU adds/kt + shfl_xor merge + 16 epilogue
// shfl broadcasts; lsum_acc[r] has the same r<->q mapping as acc[r], in-lane.
// Base otherwise = R13 minus the LDS pad (packing hypothesis falsified).
// Structure: 256 blocks x 1024 threads (16 waves), K/V staged once per
// (window, head). LDS = K[512][40] + V^T[32][536] bf16 = 73.5 KB.

namespace {
constexpr int Bn   = 8;
constexpr int Ww   = 64;
constexpr int Cc   = 128;
constexpr int HD   = 32;
constexpr int WSP  = 8;
constexpr int NTOK = 512;
constexpr int LL   = 64 * 64;
// 32^-0.5 * log2(e): exp(s) == exp2(s') with scale folded into Q
constexpr float SCALE_L2E = 0.17677669529663687f * 1.4426950408889634f;
constexpr int KPAD = 40;   // K row stride in shorts (80B rows -> 16B-aligned frags)
constexpr int VPAD = 536;  // V^T row stride in shorts (1072B rows -> 16B-aligned)
}

typedef __bf16 bf16x8 __attribute__((ext_vector_type(8)));
typedef float  f32x16 __attribute__((ext_vector_type(16)));
typedef unsigned int uint32x4 __attribute__((ext_vector_type(4)));

// dst.lo = bf16(x), dst.hi = bf16(y) — single VALU op (RNE)
__device__ inline unsigned cvtpk(float x, float y) {
    unsigned r;
    asm("v_cvt_pk_bf16_f32 %0, %1, %2" : "=v"(r) : "v"(x), "v"(y));
    return r;
}

__global__ __launch_bounds__(1024, 4) void attn_kernel(const float* __restrict__ qkv,
                                                       const float* __restrict__ cw,
                                                       const float* __restrict__ cb,
                                                       float* __restrict__ out) {
    const int blk = blockIdx.x;          // 0..255
    const int w   = blk >> 2;            // window 0..63
    const int h   = blk & 3;             // head
    const int b   = w >> 3;
    const int wb  = w & 7;
    const int tid = threadIdx.x;         // 0..1023
    const int wv  = tid >> 6;            // wave 0..15 -> 32 q rows each
    const int lane = tid & 63;
    const int l31 = lane & 31;
    const int h5  = lane >> 5;

    const float* qp = qkv;
    const float* kp = qkv + (size_t)Bn * LL * Cc;
    const float* vp = qkv + (size_t)2 * Bn * LL * Cc;

    __shared__ short K_lds[NTOK][KPAD];
    __shared__ short VT_lds[HD][VPAD];

    // ---- staging: issue ALL global loads first (T14-lite) ----
    const int tpa = tid >> 3,          ja = tid & 7;
    const int tpb = (tid + 1024) >> 3, jb = (tid + 1024) & 7;
    const int t0a = tpa * 2, t0b = tpb * 2;
    const int lqa = (t0a >> 3) * Ww + wb * WSP + (t0a & 7);
    const int lqb = (t0b >> 3) * Ww + wb * WSP + (t0b & 7);
    const size_t ga = ((size_t)b * LL + lqa) * Cc + h * HD + ja * 4;
    const size_t gb = ((size_t)b * LL + lqb) * Cc + h * HD + jb * 4;
    const float4 k0a = *reinterpret_cast<const float4*>(kp + ga);
    const float4 k1a = *reinterpret_cast<const float4*>(kp + ga + Cc);
    const float4 v0a = *reinterpret_cast<const float4*>(vp + ga);
    const float4 v1a = *reinterpret_cast<const float4*>(vp + ga + Cc);
    const float4 k0b = *reinterpret_cast<const float4*>(kp + gb);
    const float4 k1b = *reinterpret_cast<const float4*>(kp + gb + Cc);
    const float4 v0b = *reinterpret_cast<const float4*>(vp + gb);
    const float4 v1b = *reinterpret_cast<const float4*>(vp + gb + Cc);

    const int qtok = wv * 32 + l31;      // q tok; d = dc*16 + h5*8 + e
    const int qlqi = (qtok >> 3) * Ww + wb * WSP + (qtok & 7);
    const float* qptr = qp + ((size_t)b * LL + qlqi) * Cc + h * HD + h5 * 8;
    const float4 qa0 = *reinterpret_cast<const float4*>(qptr);
    const float4 qc0 = *reinterpret_cast<const float4*>(qptr + 4);
    const float4 qa1 = *reinterpret_cast<const float4*>(qptr + 16);
    const float4 qc1 = *reinterpret_cast<const float4*>(qptr + 20);

    // ---- convert + LDS write ----
    {
        uint2 pk0, pk1;
        pk0.x = cvtpk(k0a.x, k0a.y);  pk0.y = cvtpk(k0a.z, k0a.w);
        pk1.x = cvtpk(k1a.x, k1a.y);  pk1.y = cvtpk(k1a.z, k1a.w);
        *reinterpret_cast<uint2*>(&K_lds[t0a][ja * 4]) = pk0;
        *reinterpret_cast<uint2*>(&K_lds[t0a + 1][ja * 4]) = pk1;
        *reinterpret_cast<unsigned*>(&VT_lds[ja * 4 + 0][t0a]) = cvtpk(v0a.x, v1a.x);
        *reinterpret_cast<unsigned*>(&VT_lds[ja * 4 + 1][t0a]) = cvtpk(v0a.y, v1a.y);
        *reinterpret_cast<unsigned*>(&VT_lds[ja * 4 + 2][t0a]) = cvtpk(v0a.z, v1a.z);
        *reinterpret_cast<unsigned*>(&VT_lds[ja * 4 + 3][t0a]) = cvtpk(v0a.w, v1a.w);
    }
    {
        uint2 pk0, pk1;
        pk0.x = cvtpk(k0b.x, k0b.y);  pk0.y = cvtpk(k0b.z, k0b.w);
        pk1.x = cvtpk(k1b.x, k1b.y);  pk1.y = cvtpk(k1b.z, k1b.w);
        *reinterpret_cast<uint2*>(&K_lds[t0b][jb * 4]) = pk0;
        *reinterpret_cast<uint2*>(&K_lds[t0b + 1][jb * 4]) = pk1;
        *reinterpret_cast<unsigned*>(&VT_lds[jb * 4 + 0][t0b]) = cvtpk(v0b.x, v1b.x);
        *reinterpret_cast<unsigned*>(&VT_lds[jb * 4 + 1][t0b]) = cvtpk(v0b.y, v1b.y);
        *reinterpret_cast<unsigned*>(&VT_lds[jb * 4 + 2][t0b]) = cvtpk(v0b.z, v1b.z);
        *reinterpret_cast<unsigned*>(&VT_lds[jb * 4 + 3][t0b]) = cvtpk(v0b.w, v1b.w);
    }

    // ---- Q fragments ----
    bf16x8 qf[2];
    {
        uint32x4 u;
        u.x = cvtpk(qa0.x * SCALE_L2E, qa0.y * SCALE_L2E);
        u.y = cvtpk(qa0.z * SCALE_L2E, qa0.w * SCALE_L2E);
        u.z = cvtpk(qc0.x * SCALE_L2E, qc0.y * SCALE_L2E);
        u.w = cvtpk(qc0.z * SCALE_L2E, qc0.w * SCALE_L2E);
        qf[0] = __builtin_bit_cast(bf16x8, u);
        u.x = cvtpk(qa1.x * SCALE_L2E, qa1.y * SCALE_L2E);
        u.y = cvtpk(qa1.z * SCALE_L2E, qa1.w * SCALE_L2E);
        u.z = cvtpk(qc1.x * SCALE_L2E, qc1.y * SCALE_L2E);
        u.w = cvtpk(qc1.z * SCALE_L2E, qc1.w * SCALE_L2E);
        qf[1] = __builtin_bit_cast(bf16x8, u);
    }
    __syncthreads();   // the only barrier

    f32x16 acc  = (f32x16)(0.f);
    f32x16 lacc = (f32x16)(0.f);         // row-sum accumulator (ones-MFMA)
    const f32x16 z16 = (f32x16)(0.f);

    // ones B-fragment: every element bf16 1.0
    uint32x4 onesu;
    onesu.x = 0x3F803F80u; onesu.y = 0x3F803F80u;
    onesu.z = 0x3F803F80u; onesu.w = 0x3F803F80u;
    const bf16x8 onesf = __builtin_bit_cast(bf16x8, onesu);

    auto load_kf = [&](int kt, bf16x8* kf) {
        const int krow = kt * 32 + l31;
#pragma unroll
        for (int dc = 0; dc < 2; ++dc)
            kf[dc] = __builtin_bit_cast(bf16x8,
                *reinterpret_cast<const uint32x4*>(&K_lds[krow][dc * 16 + h5 * 8]));
    };

    bf16x8 kf[2];
    load_kf(0, kf);

    // ---- main loop: 16 tiles of 32 keys, barrier-free ----
    for (int kt = 0; kt < 16; ++kt) {
        f32x16 s = z16;
        s = __builtin_amdgcn_mfma_f32_32x32x16_bf16(kf[0], qf[0], s, 0, 0, 0);
        s = __builtin_amdgcn_mfma_f32_32x32x16_bf16(kf[1], qf[1], s, 0, 0, 0);
        // lane holds S^T[k][q=l31], k = (reg&3) + 8*(reg>>2) + 4*h5 + kt*32

        // prefetch next kf + this kt's V fragments while s is in flight
        bf16x8 kfn[2];
        load_kf((kt + 1) & 15, kfn);
        uint32x4 vu[2];
#pragma unroll
        for (int kw = 0; kw < 2; ++kw) {
            const int kcol = kt * 32 + kw * 16 + h5 * 8;
            vu[kw] = *reinterpret_cast<const uint32x4*>(&VT_lds[l31][kcol]);
        }

        float pe[16];
#pragma unroll
        for (int i = 0; i < 16; ++i) pe[i] = __builtin_amdgcn_exp2f(s[i]);
        unsigned dw[8];
#pragma unroll
        for (int i = 0; i < 8; ++i) dw[i] = cvtpk(pe[2 * i], pe[2 * i + 1]);

        // PV + row-sum: per 16-key window kw, redistribute P across the h5
        // halves with 2x v_permlane32_swap_b32 (vdst_hi <-> vsrc_lo), then
        // one PV MFMA and one ones-MFMA (row sums, same r<->q map as acc).
#pragma unroll
        for (int kw = 0; kw < 2; ++kw) {
            unsigned a0 = dw[4 * kw + 0], b0 = dw[4 * kw + 2];
            unsigned a1 = dw[4 * kw + 1], b1 = dw[4 * kw + 3];
            asm("v_permlane32_swap_b32 %0, %1" : "+v"(a0), "+v"(b0));
            asm("v_permlane32_swap_b32 %0, %1" : "+v"(a1), "+v"(b1));
            uint32x4 pu; pu.x = a0; pu.y = a1; pu.z = b0; pu.w = b1;
            const bf16x8 pf = __builtin_bit_cast(bf16x8, pu);
            acc  = __builtin_amdgcn_mfma_f32_32x32x16_bf16(
                pf, __builtin_bit_cast(bf16x8, vu[kw]), acc, 0, 0, 0);
            lacc = __builtin_amdgcn_mfma_f32_32x32x16_bf16(
                pf, onesf, lacc, 0, 0, 0);
        }
        kf[0] = kfn[0];
        kf[1] = kfn[1];
    }

    // ---- LePE conv: lane owns channel d = l31 of head h ----
    const int ch = h * HD + l31;
    float wreg[9];
#pragma unroll
    for (int wi = 0; wi < 9; ++wi) wreg[wi] = cw[ch * 9 + wi];
    const float bias = cb[ch];

    const int tok0 = wv * 32;
    // Packed V halo: 52 bf16 toks [tok0 + 4*h5 - 12, +40) as 26 uints.
    // Needed tap range rel. tok0+4h5 is [-9,+36]; clamped chunk slots are only
    // tokens <0 / >=512, all rowok-guarded below.
    unsigned hw[26];
    {
        const int segbase = tok0 + 4 * h5 - 12;
#pragma unroll
        for (int c2 = 0; c2 < 13; ++c2) {
            int t = segbase + 4 * c2;
            t = t < 0 ? 0 : (t > NTOK - 4 ? NTOK - 4 : t);
            const uint2 u = *reinterpret_cast<const uint2*>(&VT_lds[l31][t]);
            hw[c2 * 2 + 0] = u.x;
            hw[c2 * 2 + 1] = u.y;
        }
    }

    // ---- epilogue: normalize (in-lane rcp of lacc) + conv + store ----
#pragma unroll
    for (int r = 0; r < 16; ++r) {
        const int c_r = (r & 3) + 8 * (r >> 2);           // q row offset (compile-time)
        const float iv = __builtin_amdgcn_rcpf(lacc[r]);  // 1/lsum for q_r, in-lane
        const int tok = tok0 + c_r + 4 * h5;
        float cv = bias;
#pragma unroll
        for (int dy = -1; dy <= 1; ++dy) {
            const bool rowok = (unsigned)(tok + dy * 8) < (unsigned)NTOK;
#pragma unroll
            for (int dx = -1; dx <= 1; ++dx) {
                const int idx = c_r + 12 + dy * 8 + dx;   // compile-time, in [3,48]
                const unsigned word = hw[idx >> 1];
                const float tap = __builtin_bit_cast(float,
                    (idx & 1) ? (word & 0xFFFF0000u) : (word << 16));
                bool ok = rowok;
                if (dx == -1) ok = ok && (((r & 3) != 0) || (h5 != 0));  // wc > 0
                if (dx == +1) ok = ok && (((r & 3) != 3) || (h5 == 0));  // wc < 7
                cv += ok ? wreg[(dy + 1) * 3 + (dx + 1)] * tap : 0.f;
            }
        }
        const int lqi = (tok >> 3) * Ww + wb * WSP + (tok & 7);
        out[((size_t)b * LL + lqi) * Cc + ch] = acc[r] * iv + cv;
    }
}

extern "C" void kernel_launch(void* const* d_in, const int* in_sizes, int n_in,
                              void* d_out, int out_size, void* d_ws, size_t ws_size,
                              hipStream_t stream) {
    const float* qkv = (const float*)d_in[0];
    const float* cw  = (const float*)d_in[1];
    const float* cb  = (const float*)d_in[2];
    float* out = (float*)d_out;

    attn_kernel<<<256, 1024, 0, stream>>>(qkv, cw, cb, out);
}